// Round 6
// baseline (8676.265 us; speedup 1.0000x reference)
//
#include <hip/hip_runtime.h>
#include <math.h>

#define Bq   16
#define Tq   1024
#define INq  64
#define OUTq 64
#define Hq   512
#define Nq   128
#define Mq   40
#define SP   580      // inp row stride (floats): x[0,64) h[64,576)
#define NWGATE 128
#define NWMEM  16
#define NWG    144
#define NT     512
#define EPSq 1e-8f

typedef unsigned long long ull;

__device__ __forceinline__ float sigmf(float x){ return 1.f/(1.f + expf(-x)); }
__device__ __forceinline__ float softplusf(float x){ return (x > 20.f) ? x : log1pf(expf(x)); }

// IC-direct 64-bit tagged words: (tag<<32)|float_bits in ONE atomic word.
// Tag+payload travel together -> no fences, no store-ack waits, no flags.
__device__ __forceinline__ ull icld64(const ull* p){
  return __hip_atomic_load(p, __ATOMIC_RELAXED, __HIP_MEMORY_SCOPE_AGENT);
}
__device__ __forceinline__ void icst64(ull* p, ull v){
  __hip_atomic_store(p, v, __ATOMIC_RELAXED, __HIP_MEMORY_SCOPE_AGENT);
}
__device__ __forceinline__ ull packtv(unsigned tag, float v){
  return ((ull)tag << 32) | (ull)__float_as_uint(v);
}
__device__ __forceinline__ float lowf(ull v){ return __uint_as_float((unsigned)v); }

extern "C" __global__ void __launch_bounds__(NT, 1)
ntm_kernel(const float* __restrict__ xg,  const float* __restrict__ h0g,
           const float* __restrict__ c0g, const float* __restrict__ mem0g,
           const float* __restrict__ read0g,
           const float* __restrict__ Wih, const float* __restrict__ bih,
           const float* __restrict__ Whh, const float* __restrict__ bhh,
           const float* __restrict__ Wfc, const float* __restrict__ bfc,
           const float* __restrict__ We,  const float* __restrict__ be,
           const float* __restrict__ Wa,  const float* __restrict__ ba,
           const float* __restrict__ Wk,  const float* __restrict__ bk,
           const float* __restrict__ Wb,  const float* __restrict__ bbeta,
           float* __restrict__ yout, ull* __restrict__ h_tag,
           ull* __restrict__ r_tag)
{
  const int wg  = blockIdx.x;
  const int tid = threadIdx.x;
  __shared__ __align__(16) char smem[60992];

  if (wg < NWGATE){
    // ------- gate WG: owns h-indices [wg*4, wg*4+4) => 16 gate rows -------
    float* inp_s  = (float*)smem;               // 16 x 580 (x | h)
    float* red_s  = (float*)(smem + 37120);     // [out*17 + kseg], 4352 floats
    float* r_s    = (float*)(smem + 54528);     // 16 x 44
    float* gate_s = (float*)(smem + 57344);     // [b*16 + l]
    float* c_s    = (float*)(smem + 58368);     // [hh*16 + b]
    float* bias_s = (float*)(smem + 58624);     // 16
    float* ored_s = (float*)(smem + 58688);     // 16 x 36

    const int kseg = tid & 15;         // k-slice: 36 floats (576 = 16*36)
    const int rg   = (tid >> 4) & 3;   // h-unit; rows l = g*4+rg
    const int bg   = tid >> 6;         // batches 2*bg, 2*bg+1

    // persistent weights: 4 rows x 36 k (full VGPR file: launch_bounds(512,1))
    float4 w4[36];
    #pragma unroll
    for (int g = 0; g < 4; ++g){
      const int row = g*Hq + wg*4 + rg;
      #pragma unroll
      for (int kk = 0; kk < 9; ++kk){
        float v[4];
        #pragma unroll
        for (int c4 = 0; c4 < 4; ++c4){
          const int k = kseg*36 + kk*4 + c4;
          v[c4] = (k < 64) ? Wih[row*104 + k] : Whh[row*512 + (k - 64)];
        }
        w4[g*9 + kk] = make_float4(v[0], v[1], v[2], v[3]);
      }
    }
    float4 wr[10];                     // r-slice weights (finalize threads)
    if (tid < 256){
      const int l = tid & 15;
      const int row = (l >> 2)*Hq + wg*4 + (l & 3);
      const float* wir = Wih + row*104 + 64;
      #pragma unroll
      for (int q = 0; q < 10; ++q) wr[q] = *(const float4*)&wir[q*4];
    }
    float4 wf[4]; float bfcv = 0.f;    // out-column weights (wg<64)
    if (wg < 64){
      const int ks = tid & 31;
      #pragma unroll
      for (int q = 0; q < 4; ++q)
        wf[q] = *(const float4*)&Wfc[wg*Hq + ks*16 + q*4];
      bfcv = bfc[wg];
    }
    if (tid < 16){
      const int row = (tid >> 2)*Hq + wg*4 + (tid & 3);
      bias_s[tid] = bih[row] + bhh[row];
    }
    if (tid < 64){ const int hh = tid & 3, b = tid >> 2;
      c_s[hh*16 + b] = c0g[b*Hq + wg*4 + hh]; }
    { // stage x(0), h(-1)=h0 (pristine inputs: plain loads)
      const float4* x4 = (const float4*)xg;
      if (tid < 256){ const int b = tid >> 4, q = tid & 15;
        *(float4*)&inp_s[b*SP + q*4] = x4[(b*Tq + 0)*16 + q]; }
      const float4* h4 = (const float4*)h0g;
      #pragma unroll
      for (int j = 0; j < 4; ++j){ const int i4 = tid + 512*j;
        const int b = i4 >> 7, q = i4 & 127;
        *(float4*)&inp_s[b*SP + 64 + q*4] = h4[b*128 + q]; }
    }
    __syncthreads();

    for (int t = 0; t < Tq; ++t){
      // ---- GEMV(t) on staged {x(t), h(t-1)}: overlaps mem WGs' phase ----
      {
        float acc[4][2] = {};
        const float* base = inp_s + kseg*36;
        #pragma unroll
        for (int bl = 0; bl < 2; ++bl){
          const float* bp = base + (2*bg + bl)*SP;
          #pragma unroll
          for (int kk = 0; kk < 9; ++kk){
            const float4 f = *(const float4*)&bp[kk*4];
            #pragma unroll
            for (int g = 0; g < 4; ++g){
              acc[g][bl] += w4[g*9+kk].x*f.x + w4[g*9+kk].y*f.y
                          + w4[g*9+kk].z*f.z + w4[g*9+kk].w*f.w;
            }
          }
        }
        #pragma unroll
        for (int bl = 0; bl < 2; ++bl)
          #pragma unroll
          for (int g = 0; g < 4; ++g)
            red_s[((2*bg + bl)*16 + g*4 + rg)*17 + kseg] = acc[g][bl];
      }
      __syncthreads();                                 // A: red_s ready
      // ---- partial reduce (no r dependency) ----
      float part = 0.f;
      if (tid < 256){
        const int l = tid & 15;
        part = bias_s[l];
        const float* rp = &red_s[tid*17];
        #pragma unroll
        for (int j = 0; j < 16; ++j) part += rp[j];
      }
      // ---- acquire r(t-1): sweep-verify tagged words (t=0: pristine) ----
      if (t == 0){
        if (tid < 320){ const int b = tid/20, mp = tid - b*20;
          *(float2*)&r_s[b*44 + mp*2] = *(const float2*)&read0g[b*40 + mp*2]; }
      } else if (tid < 320){
        const unsigned want = (unsigned)t;            // (t-1)+1
        const ull* rt = r_tag + ((t-1)&1)*640;
        ull v1 = icld64(&rt[tid]);
        ull v2 = icld64(&rt[tid + 320]);
        while (((unsigned)(v1 >> 32) != want) | ((unsigned)(v2 >> 32) != want)){
          __builtin_amdgcn_s_sleep(2);
          v1 = icld64(&rt[tid]);
          v2 = icld64(&rt[tid + 320]);
        }
        { const int b = tid/40, m = tid - b*40;       r_s[b*44 + m] = lowf(v1); }
        { const int w = tid + 320, b = w/40, m = w - b*40; r_s[b*44 + m] = lowf(v2); }
      }
      __syncthreads();                                 // B: r_s ready
      if (tid < 256){
        const int fb = tid >> 4;
        float s = part;
        #pragma unroll
        for (int q = 0; q < 10; ++q){
          const float4 rv = *(const float4*)&r_s[fb*44 + q*4];
          s += wr[q].x*rv.x + wr[q].y*rv.y + wr[q].z*rv.z + wr[q].w*rv.w;
        }
        gate_s[fb*16 + (tid & 15)] = s;
      }
      __syncthreads();                                 // C: gate_s ready
      if (tid < 64){
        const int hh = tid & 3, b = tid >> 2;
        const float gi = gate_s[b*16 + hh];
        const float gf = gate_s[b*16 + 4 + hh];
        const float gc = gate_s[b*16 + 8 + hh];
        const float go = gate_s[b*16 + 12 + hh];
        const float iv = sigmf(gi), fv = sigmf(gf), gv = tanhf(gc), ov = sigmf(go);
        const float cn = fv*c_s[hh*16 + b] + iv*gv;
        const float hn = ov*tanhf(cn);
        c_s[hh*16 + b] = cn;
        icst64(&h_tag[((ull)((t&1)*16 + b))*512 + wg*4 + hh],
               packtv((unsigned)(t+1), hn));
        if (t == Tq - 1){
          yout[Bq*Tq*OUTq + b*Hq + wg*4 + hh] = hn;              // final h
          yout[Bq*Tq*OUTq + Bq*Hq + b*Hq + wg*4 + hh] = cn;      // final c
        }
      }
      // ---- out(t-1) partials: reads still-staged h(t-1); off critical path ----
      if (wg < 64 && t > 0){
        const int ob = tid >> 5, ks = tid & 31;
        float p = 0.f;
        const float* hp = &inp_s[ob*SP + 64 + ks*16];
        #pragma unroll
        for (int q = 0; q < 4; ++q){
          const float4 f = *(const float4*)&hp[q*4];
          p += wf[q].x*f.x + wf[q].y*f.y + wf[q].z*f.z + wf[q].w*f.w;
        }
        ored_s[ob*36 + ks] = p;
      }
      __syncthreads();                                 // D: h stored, ored ready
      // ---- stage h(t): one-shot sweep + verify + backoff retry ----
      {
        const unsigned want = (unsigned)(t+1);
        const ull* ht = h_tag + (ull)(t&1)*8192;
        ull v[16];
        #pragma unroll
        for (int j = 0; j < 16; ++j) v[j] = icld64(&ht[tid + 512*j]);
        // overlap the sweep's latency with the out(t-1) reduction
        if (wg < 64 && t > 0 && tid < 16){
          const float* op = &ored_s[tid*36];
          float s = bfcv;
          #pragma unroll
          for (int j = 0; j < 32; ++j) s += op[j];
          yout[(tid*Tq + (t-1))*OUTq + wg] = tanhf(s);
        }
        for (;;){
          bool ok = true;
          #pragma unroll
          for (int j = 0; j < 16; ++j)
            if ((unsigned)(v[j] >> 32) != want) ok = false;
          if (ok) break;
          __builtin_amdgcn_s_sleep(4);
          #pragma unroll
          for (int j = 0; j < 16; ++j) v[j] = icld64(&ht[tid + 512*j]);
        }
        #pragma unroll
        for (int j = 0; j < 16; ++j)
          inp_s[j*SP + 64 + tid] = lowf(v[j]);         // b=j, dim=tid
      }
      if (t + 1 < Tq && tid < 256){                    // stage x(t+1)
        const float4* x4 = (const float4*)xg;
        const int b = tid >> 4, q = tid & 15;
        *(float4*)&inp_s[b*SP + q*4] = x4[(b*Tq + (t + 1))*16 + q];
      }
      __syncthreads();                                 // E: inp_s ready
    }
    // ---- out(1023) after the loop (h(1023) is staged) ----
    if (wg < 64){
      const int ob = tid >> 5, ks = tid & 31;
      float p = 0.f;
      const float* hp = &inp_s[ob*SP + 64 + ks*16];
      #pragma unroll
      for (int q = 0; q < 4; ++q){
        const float4 f = *(const float4*)&hp[q*4];
        p += wf[q].x*f.x + wf[q].y*f.y + wf[q].z*f.z + wf[q].w*f.w;
      }
      ored_s[ob*36 + ks] = p;
      __syncthreads();
      if (tid < 16){
        const float* op = &ored_s[tid*36];
        float s = bfcv;
        #pragma unroll
        for (int j = 0; j < 32; ++j) s += op[j];
        yout[(tid*Tq + (Tq-1))*OUTq + wg] = tanhf(s);
      }
    }
  }
  else {
    // ---------------- memory workgroup: owns batch bat ----------------
    const int bat = wg - NWGATE;
    float* mem_s  = (float*)smem;               // 128 x 44
    float* h_s    = (float*)(smem + 22528);     // 512
    float* hred_s = (float*)(smem + 24576);     // 16 x 132
    float* key_s  = (float*)(smem + 33024);     // 40
    float* e_s    = (float*)(smem + 33184);     // 40
    float* a_s    = (float*)(smem + 33344);     // 40
    float* w_s    = (float*)(smem + 33504);     // 128
    float* rred_s = (float*)(smem + 34016);     // 40 x 9

    #pragma unroll
    for (int j = 0; j < 10; ++j){
      const int e = j*512 + tid;
      const int n = e / 40, m = e - n*40;
      mem_s[n*44 + m] = mem0g[bat*(Nq*Mq) + e];
    }
    const int orr = tid & 31;          // low output index
    const int kc  = tid >> 5;          // k-chunk of 32 (16 chunks)
    float4 wv2[4][8];
    #pragma unroll
    for (int g = 0; g < 4; ++g){
      const int o = orr + 32*g;
      const float* wrow = (o < 40) ? (Wk + o*Hq)
                        : (o < 80) ? (We + (o-40)*Hq)
                        : (o < 120) ? (Wa + (o-80)*Hq)
                        : (o == 120) ? Wb : nullptr;
      if (wrow){
        #pragma unroll
        for (int kk = 0; kk < 8; ++kk)
          wv2[g][kk] = *(const float4*)&wrow[kc*32 + kk*4];
      } else {
        #pragma unroll
        for (int kk = 0; kk < 8; ++kk) wv2[g][kk] = make_float4(0.f,0.f,0.f,0.f);
      }
    }
    float hb0 = 0.f, hb1 = 0.f;
    if (tid < 64){
      const int o0 = tid, o1 = tid + 64;
      hb0 = (o0 < 40) ? bk[o0] : be[o0-40];
      hb1 = (o1 < 80) ? be[o1-40] : (o1 < 120) ? ba[o1-80]
          : (o1 == 120) ? bbeta[0] : 0.f;
    }
    __syncthreads();

    for (int t = 0; t < Tq; ++t){
      const int p = t & 1;
      const unsigned want = (unsigned)(t+1);
      { // poll h(t) tagged -> h_s (512 words, own batch only)
        const ull* ht = h_tag + ((ull)(p*16 + bat))*512;
        ull v;
        do { v = icld64(&ht[tid]); } while ((unsigned)(v >> 32) != want);
        h_s[tid] = lowf(v);
      }
      __syncthreads();                                 // M1
      { // heads GEMV: 4 outputs/thread, broadcast h reads
        float a0=0.f, a1=0.f, a2=0.f, a3=0.f;
        const float* hp = h_s + kc*32;
        #pragma unroll
        for (int kk = 0; kk < 8; ++kk){
          const float4 f = *(const float4*)&hp[kk*4];
          a0 += wv2[0][kk].x*f.x + wv2[0][kk].y*f.y + wv2[0][kk].z*f.z + wv2[0][kk].w*f.w;
          a1 += wv2[1][kk].x*f.x + wv2[1][kk].y*f.y + wv2[1][kk].z*f.z + wv2[1][kk].w*f.w;
          a2 += wv2[2][kk].x*f.x + wv2[2][kk].y*f.y + wv2[2][kk].z*f.z + wv2[2][kk].w*f.w;
          a3 += wv2[3][kk].x*f.x + wv2[3][kk].y*f.y + wv2[3][kk].z*f.z + wv2[3][kk].w*f.w;
        }
        hred_s[kc*132 + orr      ] = a0;
        hred_s[kc*132 + orr + 32 ] = a1;
        hred_s[kc*132 + orr + 64 ] = a2;
        hred_s[kc*132 + orr + 96 ] = a3;
      }
      __syncthreads();                                 // M2
      if (tid < 64){ // wave 0: serial section, shuffle-reduced
        const int l = tid;
        float s0 = hb0, s1 = hb1;
        #pragma unroll
        for (int k2 = 0; k2 < 16; ++k2){
          s0 += hred_s[k2*132 + l];
          s1 += hred_s[k2*132 + l + 64];
        }
        float kv = 0.f;
        if (l < 40){ kv = tanhf(s0); key_s[l] = kv; }
        else        { e_s[l-40] = sigmf(s0); }
        if (l < 16)      e_s[l+24]  = sigmf(s1);   // o1 in [64,80)
        else if (l < 56) a_s[l-16]  = tanhf(s1);   // o1 in [80,120)
        float bval = softplusf(s1) + EPSq;          // lane 56: o1==120
        const float bet = __shfl(bval, 56);
        float ss = kv*kv;
        #pragma unroll
        for (int off = 32; off; off >>= 1) ss += __shfl_xor(ss, off);
        const float rinv = 1.f/(sqrtf(ss) + EPSq);
        float sc[2];
        #pragma unroll
        for (int half = 0; half < 2; ++half){
          const int n = l + 64*half;
          float qq = 0.f, dd = 0.f;
          const float* mrow = &mem_s[n*44];
          #pragma unroll
          for (int q = 0; q < 10; ++q){
            const float4 mv = *(const float4*)&mrow[q*4];
            const float4 kvv = *(const float4*)&key_s[q*4];
            qq += mv.x*mv.x + mv.y*mv.y + mv.z*mv.z + mv.w*mv.w;
            dd += mv.x*kvv.x + mv.y*kvv.y + mv.z*kvv.z + mv.w*kvv.w;
          }
          sc[half] = bet * dd * rinv / (sqrtf(qq) + EPSq);
        }
        float mx = fmaxf(sc[0], sc[1]);
        #pragma unroll
        for (int off = 32; off; off >>= 1) mx = fmaxf(mx, __shfl_xor(mx, off));
        const float e0 = expf(sc[0] - mx), e1 = expf(sc[1] - mx);
        float sm = e0 + e1;
        #pragma unroll
        for (int off = 32; off; off >>= 1) sm += __shfl_xor(sm, off);
        const float inv = 1.f/sm;
        w_s[l] = e0*inv; w_s[l+64] = e1*inv;
      }
      __syncthreads();                                 // M3
      if (tid < 320){ // fused erase/add update + read partials
        const int m = tid % 40, ng = tid / 40;
        const float ev = e_s[m], av = a_s[m];
        float part = 0.f;
        #pragma unroll
        for (int j = 0; j < 16; ++j){
          const int n = ng*16 + j, idx = n*44 + m;
          const float mv = mem_s[idx];
          const float wn = w_s[n];
          const float nv = fmaf(wn, fmaf(-ev, mv, av), mv);
          mem_s[idx] = nv;
          part = fmaf(wn, nv, part);
        }
        rred_s[m*9 + ng] = part;
      }
      __syncthreads();                                 // M4
      if (tid < 40){
        float r = 0.f;
        #pragma unroll
        for (int j = 0; j < 8; ++j) r += rred_s[tid*9 + j];
        icst64(&r_tag[(p*16 + bat)*40 + tid], packtv(want, r));
      }
    }
  }
}

extern "C" void kernel_launch(void* const* d_in, const int* in_sizes, int n_in,
                              void* d_out, int out_size, void* d_ws, size_t ws_size,
                              hipStream_t stream){
  const float* xg    = (const float*)d_in[0];
  const float* h0g   = (const float*)d_in[1];
  const float* c0g   = (const float*)d_in[2];
  const float* mem0g = (const float*)d_in[3];
  const float* read0g= (const float*)d_in[4];
  const float* Wih   = (const float*)d_in[5];
  const float* bih   = (const float*)d_in[6];
  const float* Whh   = (const float*)d_in[7];
  const float* bhh   = (const float*)d_in[8];
  const float* Wfc   = (const float*)d_in[9];
  const float* bfc   = (const float*)d_in[10];
  const float* We    = (const float*)d_in[11];
  const float* be    = (const float*)d_in[12];
  const float* Wa    = (const float*)d_in[13];
  const float* ba    = (const float*)d_in[14];
  const float* Wk    = (const float*)d_in[15];
  const float* bk    = (const float*)d_in[16];
  const float* Wb    = (const float*)d_in[17];
  const float* bbeta = (const float*)d_in[18];

  float* yout  = (float*)d_out;
  ull*   h_tag = (ull*)d_ws;                       // 2*16*512 ull = 128 KiB
  ull*   r_tag = (ull*)((char*)d_ws + 131072);     // 2*16*40 ull = 10 KiB

  hipMemsetAsync(d_ws, 0, 141312, stream);         // tags=0 != any want (1..1024)
  hipLaunchKernelGGL(ntm_kernel, dim3(NWG), dim3(NT), 0, stream,
                     xg, h0g, c0g, mem0g, read0g, Wih, bih, Whh, bhh,
                     Wfc, bfc, We, be, Wa, ba, Wk, bk, Wb, bbeta,
                     yout, h_tag, r_tag);
}

// Round 7
// 6999.563 us; speedup vs baseline: 1.2395x; 1.2395x over previous
//
#include <hip/hip_runtime.h>
#include <math.h>

#define Bq   16
#define Tq   1024
#define INq  64
#define OUTq 64
#define Hq   512
#define Nq   128
#define Mq   40
#define SP   580      // inp row stride (floats): x[0,64) h[64,576)
#define NWGATE 128
#define NWMEM  16
#define NWG    144
#define NT     512
#define EPSq 1e-8f

typedef unsigned long long ull;

__device__ __forceinline__ float sigmf(float x){ return 1.f/(1.f + expf(-x)); }
__device__ __forceinline__ float softplusf(float x){ return (x > 20.f) ? x : log1pf(expf(x)); }

// IC-direct 64-bit tagged words: (tag<<32)|float_bits in ONE atomic word.
__device__ __forceinline__ ull icld64(const ull* p){
  return __hip_atomic_load(p, __ATOMIC_RELAXED, __HIP_MEMORY_SCOPE_AGENT);
}
__device__ __forceinline__ void icst64(ull* p, ull v){
  __hip_atomic_store(p, v, __ATOMIC_RELAXED, __HIP_MEMORY_SCOPE_AGENT);
}
__device__ __forceinline__ ull packtv(unsigned tag, float v){
  return ((ull)tag << 32) | (ull)__float_as_uint(v);
}
__device__ __forceinline__ float lowf(ull v){ return __uint_as_float((unsigned)v); }

extern "C" __global__ void __launch_bounds__(NT, 1)
ntm_kernel(const float* __restrict__ xg,  const float* __restrict__ h0g,
           const float* __restrict__ c0g, const float* __restrict__ mem0g,
           const float* __restrict__ read0g,
           const float* __restrict__ Wih, const float* __restrict__ bih,
           const float* __restrict__ Whh, const float* __restrict__ bhh,
           const float* __restrict__ Wfc, const float* __restrict__ bfc,
           const float* __restrict__ We,  const float* __restrict__ be,
           const float* __restrict__ Wa,  const float* __restrict__ ba,
           const float* __restrict__ Wk,  const float* __restrict__ bk,
           const float* __restrict__ Wb,  const float* __restrict__ bbeta,
           float* __restrict__ yout, ull* __restrict__ h_tag,
           ull* __restrict__ r_rep, ull* __restrict__ h_okr)
{
  const int wg  = blockIdx.x;
  const int tid = threadIdx.x;
  __shared__ __align__(16) char smem[60992];

  if (wg < NWGATE){
    // ------- gate WG: owns h-indices [wg*4, wg*4+4) => 16 gate rows -------
    float* inp_s  = (float*)smem;               // 16 x 580 (x | h)
    float* red_s  = (float*)(smem + 37120);     // [out*17 + kseg], 4352 floats
    float* r_s    = (float*)(smem + 54528);     // 16 x 44
    float* gate_s = (float*)(smem + 57344);     // [b*16 + l]
    float* c_s    = (float*)(smem + 58368);     // [hh*16 + b]
    float* bias_s = (float*)(smem + 58624);     // 16
    float* ored_s = (float*)(smem + 58688);     // 16 x 36

    const int kseg = tid & 15;         // k-slice: 36 floats (576 = 16*36)
    const int rg   = (tid >> 4) & 3;   // h-unit; rows l = g*4+rg
    const int bg   = tid >> 6;         // batches 2*bg, 2*bg+1
    const int rep  = wg & 7;           // which replica this WG polls

    // persistent weights: 4 rows x 36 k
    float4 w4[36];
    #pragma unroll
    for (int g = 0; g < 4; ++g){
      const int row = g*Hq + wg*4 + rg;
      #pragma unroll
      for (int kk = 0; kk < 9; ++kk){
        float v[4];
        #pragma unroll
        for (int c4 = 0; c4 < 4; ++c4){
          const int k = kseg*36 + kk*4 + c4;
          v[c4] = (k < 64) ? Wih[row*104 + k] : Whh[row*512 + (k - 64)];
        }
        w4[g*9 + kk] = make_float4(v[0], v[1], v[2], v[3]);
      }
    }
    float4 wr[10];                     // r-slice weights (finalize threads)
    if (tid < 256){
      const int l = tid & 15;
      const int row = (l >> 2)*Hq + wg*4 + (l & 3);
      const float* wir = Wih + row*104 + 64;
      #pragma unroll
      for (int q = 0; q < 10; ++q) wr[q] = *(const float4*)&wir[q*4];
    }
    float4 wf[4]; float bfcv = 0.f;    // out-column weights (wg<64)
    if (wg < 64){
      const int ks = tid & 31;
      #pragma unroll
      for (int q = 0; q < 4; ++q)
        wf[q] = *(const float4*)&Wfc[wg*Hq + ks*16 + q*4];
      bfcv = bfc[wg];
    }
    if (tid < 16){
      const int row = (tid >> 2)*Hq + wg*4 + (tid & 3);
      bias_s[tid] = bih[row] + bhh[row];
    }
    if (tid < 64){ const int hh = tid & 3, b = tid >> 2;
      c_s[hh*16 + b] = c0g[b*Hq + wg*4 + hh]; }
    { // stage x(0), h(-1)=h0 (pristine inputs: plain loads)
      const float4* x4 = (const float4*)xg;
      if (tid < 256){ const int b = tid >> 4, q = tid & 15;
        *(float4*)&inp_s[b*SP + q*4] = x4[(b*Tq + 0)*16 + q]; }
      const float4* h4 = (const float4*)h0g;
      #pragma unroll
      for (int j = 0; j < 4; ++j){ const int i4 = tid + 512*j;
        const int b = i4 >> 7, q = i4 & 127;
        *(float4*)&inp_s[b*SP + 64 + q*4] = h4[b*128 + q]; }
    }
    __syncthreads();

    for (int t = 0; t < Tq; ++t){
      // ---- GEMV(t) on staged {x(t), h(t-1)}: overlaps mem WGs' phase ----
      {
        float acc[4][2] = {};
        const float* base = inp_s + kseg*36;
        #pragma unroll
        for (int bl = 0; bl < 2; ++bl){
          const float* bp = base + (2*bg + bl)*SP;
          #pragma unroll
          for (int kk = 0; kk < 9; ++kk){
            const float4 f = *(const float4*)&bp[kk*4];
            #pragma unroll
            for (int g = 0; g < 4; ++g){
              acc[g][bl] += w4[g*9+kk].x*f.x + w4[g*9+kk].y*f.y
                          + w4[g*9+kk].z*f.z + w4[g*9+kk].w*f.w;
            }
          }
        }
        #pragma unroll
        for (int bl = 0; bl < 2; ++bl)
          #pragma unroll
          for (int g = 0; g < 4; ++g)
            red_s[((2*bg + bl)*16 + g*4 + rg)*17 + kseg] = acc[g][bl];
      }
      __syncthreads();                                 // A: red_s ready
      // ---- partial reduce (no r dependency) ----
      float part = 0.f;
      if (tid < 256){
        part = bias_s[tid & 15];
        const float* rp = &red_s[tid*17];
        #pragma unroll
        for (int j = 0; j < 16; ++j) part += rp[j];
      }
      // ---- acquire r(t-1) from own replica (t=0: pristine read0) ----
      if (t == 0){
        if (tid < 320){ const int b = tid/20, mp = tid - b*20;
          *(float2*)&r_s[b*44 + mp*2] = *(const float2*)&read0g[b*40 + mp*2]; }
      } else if (tid < 320){
        const unsigned want = (unsigned)t;            // (t-1)+1
        const ull* rt = r_rep + (ull)(rep*2 + ((t-1)&1))*640;
        ull v1 = icld64(&rt[tid]);
        ull v2 = icld64(&rt[tid + 320]);
        while (((unsigned)(v1 >> 32) != want) | ((unsigned)(v2 >> 32) != want)){
          __builtin_amdgcn_s_sleep(2);
          v1 = icld64(&rt[tid]);
          v2 = icld64(&rt[tid + 320]);
        }
        { const int b = tid/40, m = tid - b*40;       r_s[b*44 + m] = lowf(v1); }
        { const int w = tid + 320, b = w/40, m = w - b*40; r_s[b*44 + m] = lowf(v2); }
      }
      __syncthreads();                                 // B: r_s ready
      if (tid < 256){
        const int fb = tid >> 4;
        float s = part;
        #pragma unroll
        for (int q = 0; q < 10; ++q){
          const float4 rv = *(const float4*)&r_s[fb*44 + q*4];
          s += wr[q].x*rv.x + wr[q].y*rv.y + wr[q].z*rv.z + wr[q].w*rv.w;
        }
        gate_s[fb*16 + (tid & 15)] = s;
      }
      __syncthreads();                                 // C: gate_s ready
      if (tid < 64){
        const int hh = tid & 3, b = tid >> 2;
        const float gi = gate_s[b*16 + hh];
        const float gf = gate_s[b*16 + 4 + hh];
        const float gc = gate_s[b*16 + 8 + hh];
        const float go = gate_s[b*16 + 12 + hh];
        const float iv = sigmf(gi), fv = sigmf(gf), gv = tanhf(gc), ov = sigmf(go);
        const float cn = fv*c_s[hh*16 + b] + iv*gv;
        const float hn = ov*tanhf(cn);
        c_s[hh*16 + b] = cn;
        icst64(&h_tag[((ull)((t&1)*16 + b))*512 + wg*4 + hh],
               packtv((unsigned)(t+1), hn));
        if (t == Tq - 1){
          yout[Bq*Tq*OUTq + b*Hq + wg*4 + hh] = hn;              // final h
          yout[Bq*Tq*OUTq + Bq*Hq + b*Hq + wg*4 + hh] = cn;      // final c
        }
      }
      // ---- out(t-1) partials from still-staged h(t-1) (off critical path) ----
      if (wg < 64 && t > 0){
        const int ob = tid >> 5, ks = tid & 31;
        float p = 0.f;
        const float* hp = &inp_s[ob*SP + 64 + ks*16];
        #pragma unroll
        for (int q = 0; q < 4; ++q){
          const float4 f = *(const float4*)&hp[q*4];
          p += wf[q].x*f.x + wf[q].y*f.y + wf[q].z*f.z + wf[q].w*f.w;
        }
        ored_s[ob*36 + ks] = p;
      }
      // ---- h(t): poll own replica flag, then ONE bulk load ----
      {
        const unsigned want = (unsigned)(t+1);
        if (tid < 16){
          const ull* fp = &h_okr[(ull)(rep*2 + (t&1))*16 + tid];
          while ((unsigned)(icld64(fp) >> 32) != want)
            __builtin_amdgcn_s_sleep(2);
        }
        __syncthreads();                               // flags ok; ored_s ready
        const ull* ht = h_tag + (ull)(t&1)*8192;
        ull v[16];
        #pragma unroll
        for (int j = 0; j < 16; ++j) v[j] = icld64(&ht[tid + 512*j]);
        if (wg < 64 && t > 0 && tid < 16){             // out(t-1) reduce in load shadow
          const float* op = &ored_s[tid*36];
          float s = bfcv;
          #pragma unroll
          for (int j = 0; j < 32; ++j) s += op[j];
          yout[(tid*Tq + (t-1))*OUTq + wg] = tanhf(s);
        }
        #pragma unroll
        for (int j = 0; j < 16; ++j)
          inp_s[j*SP + 64 + tid] = lowf(v[j]);         // b=j, dim=tid
      }
      if (t + 1 < Tq && tid < 256){                    // stage x(t+1)
        const float4* x4 = (const float4*)xg;
        const int b = tid >> 4, q = tid & 15;
        *(float4*)&inp_s[b*SP + q*4] = x4[(b*Tq + (t + 1))*16 + q];
      }
      __syncthreads();                                 // E: inp_s ready
    }
    // ---- out(1023) after the loop (h(1023) staged in inp_s) ----
    if (wg < 64){
      const int ob = tid >> 5, ks = tid & 31;
      float p = 0.f;
      const float* hp = &inp_s[ob*SP + 64 + ks*16];
      #pragma unroll
      for (int q = 0; q < 4; ++q){
        const float4 f = *(const float4*)&hp[q*4];
        p += wf[q].x*f.x + wf[q].y*f.y + wf[q].z*f.z + wf[q].w*f.w;
      }
      ored_s[ob*36 + ks] = p;
      __syncthreads();
      if (tid < 16){
        const float* op = &ored_s[tid*36];
        float s = bfcv;
        #pragma unroll
        for (int j = 0; j < 32; ++j) s += op[j];
        yout[(tid*Tq + (Tq-1))*OUTq + wg] = tanhf(s);
      }
    }
  }
  else {
    // ---------------- memory workgroup: owns batch bat ----------------
    const int bat = wg - NWGATE;
    float* mem_s  = (float*)smem;               // 128 x 44
    float* h_s    = (float*)(smem + 22528);     // 512
    float* hred_s = (float*)(smem + 24576);     // 128 x 4
    float* key_s  = (float*)(smem + 26624);     // 40
    float* e_s    = (float*)(smem + 26784);     // 40
    float* a_s    = (float*)(smem + 26944);     // 40
    float* w_s    = (float*)(smem + 27104);     // 128
    float* rred_s = (float*)(smem + 27616);     // 40 x 9

    #pragma unroll
    for (int j = 0; j < 10; ++j){
      const int e = j*512 + tid;
      const int n = e / 40, m = e - n*40;
      mem_s[n*44 + m] = mem0g[bat*(Nq*Mq) + e];
    }
    const int o  = tid & 127;          // output index (121 live)
    const int kc = tid >> 7;           // k-chunk of 128 dims (4 chunks)
    const float* wrow = (o < 40) ? (Wk + o*Hq)
                      : (o < 80) ? (We + (o-40)*Hq)
                      : (o < 120) ? (Wa + (o-80)*Hq)
                      : (o == 120) ? Wb : nullptr;
    float4 wv2[32];
    if (wrow){
      #pragma unroll
      for (int kk = 0; kk < 32; ++kk)
        wv2[kk] = *(const float4*)&wrow[kc*128 + kk*4];
    } else {
      #pragma unroll
      for (int kk = 0; kk < 32; ++kk) wv2[kk] = make_float4(0.f,0.f,0.f,0.f);
    }
    float hb0 = 0.f, hb1 = 0.f;
    if (tid < 64){
      const int o0 = tid, o1 = tid + 64;
      hb0 = (o0 < 40) ? bk[o0] : be[o0-40];
      hb1 = (o1 < 80) ? be[o1-40] : (o1 < 120) ? ba[o1-80]
          : (o1 == 120) ? bbeta[0] : 0.f;
    }
    __syncthreads();

    for (int t = 0; t < Tq; ++t){
      const int p = t & 1;
      const unsigned want = (unsigned)(t+1);
      { // poll h(t) tagged -> h_s (512 words, own batch only; 1 reader/word)
        const ull* ht = h_tag + ((ull)(p*16 + bat))*512;
        ull v;
        do { v = icld64(&ht[tid]); } while ((unsigned)(v >> 32) != want);
        h_s[tid] = lowf(v);
      }
      __syncthreads();                                 // M1
      if (tid < 8)                                     // publish h_ok replicas
        icst64(&h_okr[(ull)(tid*2 + p)*16 + bat], packtv(want, 0.f));
      { // heads GEMV: 1 output x 4 k-chunks per thread
        float a0 = 0.f;
        const float* hp = h_s + kc*128;
        #pragma unroll
        for (int kk = 0; kk < 32; ++kk){
          const float4 f = *(const float4*)&hp[kk*4];
          a0 += wv2[kk].x*f.x + wv2[kk].y*f.y + wv2[kk].z*f.z + wv2[kk].w*f.w;
        }
        hred_s[o*4 + kc] = a0;
      }
      __syncthreads();                                 // M2
      if (tid < 64){ // wave 0: serial section, shuffle-reduced
        const int l = tid;
        const float4 p0 = *(const float4*)&hred_s[l*4];
        const float4 p1 = *(const float4*)&hred_s[(l+64)*4];
        float s0 = hb0 + p0.x + p0.y + p0.z + p0.w;
        float s1 = hb1 + p1.x + p1.y + p1.z + p1.w;
        float kv = 0.f;
        if (l < 40){ kv = tanhf(s0); key_s[l] = kv; }
        else        { e_s[l-40] = sigmf(s0); }
        if (l < 16)      e_s[l+24]  = sigmf(s1);   // o1 in [64,80)
        else if (l < 56) a_s[l-16]  = tanhf(s1);   // o1 in [80,120)
        float bval = softplusf(s1) + EPSq;          // lane 56: o1==120
        const float bet = __shfl(bval, 56);
        float ss = kv*kv;
        #pragma unroll
        for (int off = 32; off; off >>= 1) ss += __shfl_xor(ss, off);
        const float rinv = 1.f/(sqrtf(ss) + EPSq);
        float sc[2];
        #pragma unroll
        for (int half = 0; half < 2; ++half){
          const int n = l + 64*half;
          float qq = 0.f, dd = 0.f;
          const float* mrow = &mem_s[n*44];
          #pragma unroll
          for (int q = 0; q < 10; ++q){
            const float4 mv = *(const float4*)&mrow[q*4];
            const float4 kvv = *(const float4*)&key_s[q*4];
            qq += mv.x*mv.x + mv.y*mv.y + mv.z*mv.z + mv.w*mv.w;
            dd += mv.x*kvv.x + mv.y*kvv.y + mv.z*kvv.z + mv.w*kvv.w;
          }
          sc[half] = bet * dd * rinv / (sqrtf(qq) + EPSq);
        }
        float mx = fmaxf(sc[0], sc[1]);
        #pragma unroll
        for (int off = 32; off; off >>= 1) mx = fmaxf(mx, __shfl_xor(mx, off));
        const float e0 = expf(sc[0] - mx), e1 = expf(sc[1] - mx);
        float sm = e0 + e1;
        #pragma unroll
        for (int off = 32; off; off >>= 1) sm += __shfl_xor(sm, off);
        const float inv = 1.f/sm;
        w_s[l] = e0*inv; w_s[l+64] = e1*inv;
      }
      __syncthreads();                                 // M3
      if (tid < 320){ // fused erase/add update + read partials
        const int m = tid % 40, ng = tid / 40;
        const float ev = e_s[m], av = a_s[m];
        float part = 0.f;
        #pragma unroll
        for (int j = 0; j < 16; ++j){
          const int n = ng*16 + j, idx = n*44 + m;
          const float mv = mem_s[idx];
          const float wn = w_s[n];
          const float nv = fmaf(wn, fmaf(-ev, mv, av), mv);
          mem_s[idx] = nv;
          part = fmaf(wn, nv, part);
        }
        rred_s[m*9 + ng] = part;
      }
      __syncthreads();                                 // M4
      if (tid < 40){
        float r = 0.f;
        #pragma unroll
        for (int j = 0; j < 8; ++j) r += rred_s[tid*9 + j];
        const ull pv = packtv(want, r);
        #pragma unroll
        for (int rp2 = 0; rp2 < 8; ++rp2)
          icst64(&r_rep[(ull)(rp2*2 + p)*640 + bat*40 + tid], pv);
      }
    }
  }
}

extern "C" void kernel_launch(void* const* d_in, const int* in_sizes, int n_in,
                              void* d_out, int out_size, void* d_ws, size_t ws_size,
                              hipStream_t stream){
  const float* xg    = (const float*)d_in[0];
  const float* h0g   = (const float*)d_in[1];
  const float* c0g   = (const float*)d_in[2];
  const float* mem0g = (const float*)d_in[3];
  const float* read0g= (const float*)d_in[4];
  const float* Wih   = (const float*)d_in[5];
  const float* bih   = (const float*)d_in[6];
  const float* Whh   = (const float*)d_in[7];
  const float* bhh   = (const float*)d_in[8];
  const float* Wfc   = (const float*)d_in[9];
  const float* bfc   = (const float*)d_in[10];
  const float* We    = (const float*)d_in[11];
  const float* be    = (const float*)d_in[12];
  const float* Wa    = (const float*)d_in[13];
  const float* ba    = (const float*)d_in[14];
  const float* Wk    = (const float*)d_in[15];
  const float* bk    = (const float*)d_in[16];
  const float* Wb    = (const float*)d_in[17];
  const float* bbeta = (const float*)d_in[18];

  float* yout  = (float*)d_out;
  ull*   h_tag = (ull*)d_ws;                       // 2*16*512 = 16384 ull
  ull*   r_rep = (ull*)((char*)d_ws + 131072);     // 8 rep x 2 par x 640 = 10240 ull
  ull*   h_okr = (ull*)((char*)d_ws + 212992);     // 8 rep x 2 par x 16 = 256 ull

  hipMemsetAsync(d_ws, 0, 215040, stream);         // tags=0 != any want (1..1024)
  hipLaunchKernelGGL(ntm_kernel, dim3(NWG), dim3(NT), 0, stream,
                     xg, h0g, c0g, mem0g, read0g, Wih, bih, Whh, bhh,
                     Wfc, bfc, We, be, Wa, ba, Wk, bk, Wb, bbeta,
                     yout, h_tag, r_rep, h_okr);
}